// Round 1
// baseline (435.812 us; speedup 1.0000x reference)
//
#include <hip/hip_runtime.h>

// WTConv2d fused (see R0 derivation):
// out = (conv3x3(x, base_w)+base_b)*base_scale
//     + wavelet_scale * U( U(conv3x3(t1, ws1)) + conv3x3(t0, ws0) )
// t0 = D(x), t1 = D(t0); D = stride-2 2x2 corr, +-0.25 signs by c>>6;
// U = 2x upsample, +-0.5 signs by c>>6; ws1 = w_ll+w_lh1+w_hl1+w_hh1,
// ws0 = w_lh0+w_hl0+w_hh0.
//
// R2 -> R3: remove xs from LDS entirely. Phase 6 re-reads its 6x6 patch
// straight from global (L1/L2-hot: phase 1 fetched the same tile) as
// b32+b128+b32 per row with a rolling 3-row window. This kills the
// structural phase-6 bank conflicts (col stride 4 pinned reads to 8 banks
// regardless of xs padding) and cuts LDS 27.1KB -> 9.7KB so occupancy is
// wave-capped at 8 blocks/CU (__launch_bounds__(256,8), VGPR<=64).

#define HH 224
#define WW 224
#define CC 256
#define BB 4
#define T0_S 36   // t0s row stride

__global__ __launch_bounds__(256, 8) void wtconv_fused(
    const float* __restrict__ x,
    const float* __restrict__ base_w,
    const float* __restrict__ base_b,
    const float* __restrict__ base_scale,
    const float* __restrict__ wavelet_scale,
    const float* __restrict__ w_ll,
    const float* __restrict__ w_lh0,
    const float* __restrict__ w_hl0,
    const float* __restrict__ w_hh0,
    const float* __restrict__ w_lh1,
    const float* __restrict__ w_hl1,
    const float* __restrict__ w_hh1,
    float* __restrict__ out)
{
    __shared__ float t0s[32][T0_S];  // t0 rows [A0-2, A0+30)
    __shared__ float t1s[16][18];    // t1 rows [A1-1, A1+15)
    __shared__ float a1s[14][14];    // a1 rows [A1, A1+14)
    __shared__ float a0s[28][28];    // a0 rows [A0, A0+28)
    // total 4608+1152+784+3136 = 9680 B -> wave-capped 8 blocks/CU

    const int tid  = threadIdx.x;
    const int bid  = blockIdx.x;
    const int tile = bid & 15;
    const int c    = (bid >> 4) & 255;
    const int b    = bid >> 12;
    const int tj   = tile & 3;
    const int ti   = tile >> 2;
    const int R0   = ti * 56;
    const int C0   = tj * 56;

    const int f = c >> 6;                   // faithful quirk: filter idx = c//64
    const float sR = (f & 1) ? -1.f : 1.f;
    const float sC = (f & 2) ? -1.f : 1.f;

    float ws1[9], ws0[9], bw[9];
#pragma unroll
    for (int j = 0; j < 9; ++j) {
        const int o = c * 9 + j;
        ws1[j] = w_ll[o] + w_lh1[o] + w_hl1[o] + w_hh1[o];
        ws0[j] = w_lh0[o] + w_hl0[o] + w_hh0[o];
        bw[j]  = base_w[o];
    }
    const float bb  = base_b[c];
    const float bsc = base_scale[c];
    const float wsc = wavelet_scale[c];

    const float* xp = x   + (size_t)(b * CC + c) * (HH * WW);
    float*       op = out + (size_t)(b * CC + c) * (HH * WW);

    // ---- Phase 1+2: load 64x64 x tile to REGISTERS and compute t0 ----
    // thread: col-group k (float4), row-pair rp; its 4 iterations cover rows
    // {2rp, 2rp+1, 2rp+32, 2rp+33} -> vertical pairs live in one thread.
    {
        const int k  = tid & 15;
        const int rp = tid >> 4;
        const int gc = C0 - 4 + 4 * k;
        const bool cok = (gc >= 0) & (gc < WW);
        float4 v0 = make_float4(0.f, 0.f, 0.f, 0.f);
#pragma unroll
        for (int it = 0; it < 4; ++it) {
            const int row = 2 * rp + (it & 1) + 32 * (it >> 1);
            const int gr  = R0 - 4 + row;
            float4 v = make_float4(0.f, 0.f, 0.f, 0.f);
            if (cok && gr >= 0 && gr < HH)
                v = *(const float4*)(xp + gr * WW + gc);
            if (it & 1) {
                const float e = (v0.x + sC * v0.y) + sR * (v.x + sC * v.y);
                const float o = (v0.z + sC * v0.w) + sR * (v.z + sC * v.w);
                const int t0r = rp + 16 * (it >> 1);
                *(float2*)&t0s[t0r][2 * k] = make_float2(0.25f * e, 0.25f * o);
            } else {
                v0 = v;
            }
        }
    }
    __syncthreads();

    // ---- Phase 3: t1 = D(t0), 16x16, 4 cols/thread (1 wave) ----
    if (tid < 64) {
        const int m = tid >> 2;
        const int n = 4 * (tid & 3);
        const float4 A  = *(const float4*)&t0s[2 * m][2 * n];
        const float4 Bq = *(const float4*)&t0s[2 * m][2 * n + 4];
        const float4 Cq = *(const float4*)&t0s[2 * m + 1][2 * n];
        const float4 Dq = *(const float4*)&t0s[2 * m + 1][2 * n + 4];
        const float v0v = 0.25f * ((A.x + sC * A.y) + sR * (Cq.x + sC * Cq.y));
        const float v1v = 0.25f * ((A.z + sC * A.w) + sR * (Cq.z + sC * Cq.w));
        const float v2v = 0.25f * ((Bq.x + sC * Bq.y) + sR * (Dq.x + sC * Dq.y));
        const float v3v = 0.25f * ((Bq.z + sC * Bq.w) + sR * (Dq.z + sC * Dq.w));
        *(float2*)&t1s[m][n]     = make_float2(v0v, v1v);
        *(float2*)&t1s[m][n + 2] = make_float2(v2v, v3v);
    }
    __syncthreads();

    // ---- Phase 4: a1 = conv3x3(t1, ws1), 14x14, 2 cols/thread ----
    if (tid < 98) {
        const int k = tid / 7;
        const int l = 2 * (tid % 7);
        float acc0 = 0.f, acc1 = 0.f;
#pragma unroll
        for (int u = 0; u < 3; ++u) {
            const float2 p = *(const float2*)&t1s[k + u][l];
            const float2 q = *(const float2*)&t1s[k + u][l + 2];
            acc0 += p.x * ws1[3 * u] + p.y * ws1[3 * u + 1] + q.x * ws1[3 * u + 2];
            acc1 += p.y * ws1[3 * u] + q.x * ws1[3 * u + 1] + q.y * ws1[3 * u + 2];
        }
        *(float2*)&a1s[k][l] = make_float2(acc0, acc1);
    }
    __syncthreads();

    // ---- Phase 5: a0 = U(a1) + conv3x3(t0, ws0), 28x28, 4 cols/thread ----
    if (tid < 196) {
        const int i  = tid / 7;
        const int j7 = tid % 7;
        const int j  = 4 * j7;
        float a0 = 0.f, a1v = 0.f, a2 = 0.f, a3 = 0.f;
#pragma unroll
        for (int u = 0; u < 3; ++u) {
            const float4 A  = *(const float4*)&t0s[i + 1 + u][j];
            const float4 Bq = *(const float4*)&t0s[i + 1 + u][j + 4];
            const float c1 = A.y, c2 = A.z, c3 = A.w, c4 = Bq.x, c5 = Bq.y, c6 = Bq.z;
            const float w0 = ws0[3 * u], w1 = ws0[3 * u + 1], w2 = ws0[3 * u + 2];
            a0  += c1 * w0 + c2 * w1 + c3 * w2;
            a1v += c2 * w0 + c3 * w1 + c4 * w2;
            a2  += c3 * w0 + c4 * w1 + c5 * w2;
            a3  += c4 * w0 + c5 * w1 + c6 * w2;
        }
        const float2 ap = *(const float2*)&a1s[i >> 1][2 * j7];
        const float e = 0.5f * ((i & 1) ? sR : 1.f);
        const float o = e * sC;
        float4 r;
        r.x = a0  + e * ap.x;
        r.y = a1v + o * ap.x;
        r.z = a2  + o * 0.f + e * ap.y;   // keep layout identical; see below
        r.w = a3  + o * ap.y;
        r.z = a2  + e * ap.y;
        *(float4*)&a0s[i][j] = r;
    }
    __syncthreads();

    // ---- Phase 6: out = (conv3x3(x,bw)+bb)*bsc + wsc*U(a0) ----
    // 4x4 patch/thread; x read DIRECTLY from global (L1/L2-hot tile),
    // rolling 3-row window, b32+b128+b32 per row (24B exact, all aligned).
    if (tid < 196) {
        const int cg   = tid % 14;
        const int band = tid / 14;
        const int r0   = 4 * band;
        const int gc0  = C0 + 4 * cg;           // b128 col base, always in [0,220]
        const bool cokL = (gc0 - 1) >= 0;
        const bool cokR = (gc0 + 4) < WW;
        const int gr0  = R0 + r0 - 1;           // first tap row

        float h0[6], h1[6], h2[6];

#define LOADROW(h, rr_) do {                                                  \
            const int gr_ = gr0 + (rr_);                                      \
            if ((unsigned)gr_ < (unsigned)HH) {                               \
                const float* rp_ = xp + (size_t)gr_ * WW + gc0;               \
                const float4 q_ = *(const float4*)rp_;                        \
                (h)[0] = cokL ? rp_[-1] : 0.f;                                \
                (h)[1] = q_.x; (h)[2] = q_.y; (h)[3] = q_.z; (h)[4] = q_.w;   \
                (h)[5] = cokR ? rp_[4] : 0.f;                                 \
            } else {                                                          \
                (h)[0] = (h)[1] = (h)[2] = 0.f;                               \
                (h)[3] = (h)[4] = (h)[5] = 0.f;                               \
            }                                                                 \
        } while (0)

        LOADROW(h0, 0);
        LOADROW(h1, 1);

        const float we = wsc * 0.5f;
#pragma unroll
        for (int rr = 0; rr < 4; ++rr) {
            LOADROW(h2, rr + 2);
            float acc[4];
#pragma unroll
            for (int t = 0; t < 4; ++t) {
                acc[t] = h0[t]     * bw[0] + h0[t + 1] * bw[1] + h0[t + 2] * bw[2]
                       + h1[t]     * bw[3] + h1[t + 1] * bw[4] + h1[t + 2] * bw[5]
                       + h2[t]     * bw[6] + h2[t + 1] * bw[7] + h2[t + 2] * bw[8];
            }
            const int r = r0 + rr;
            const float2 ap = *(const float2*)&a0s[r >> 1][2 * cg];
            const float w0 = (r & 1) ? we * sR : we;
            const float w1 = w0 * sC;
            float4 o;
            o.x = (acc[0] + bb) * bsc + w0 * ap.x;
            o.y = (acc[1] + bb) * bsc + w1 * ap.x;
            o.z = (acc[2] + bb) * bsc + w0 * ap.y;
            o.w = (acc[3] + bb) * bsc + w1 * ap.y;
            *(float4*)(op + (size_t)(R0 + r) * WW + gc0) = o;

            if (rr < 3) {
#pragma unroll
                for (int j = 0; j < 6; ++j) { h0[j] = h1[j]; h1[j] = h2[j]; }
            }
        }
#undef LOADROW
    }
}

extern "C" void kernel_launch(void* const* d_in, const int* in_sizes, int n_in,
                              void* d_out, int out_size, void* d_ws, size_t ws_size,
                              hipStream_t stream) {
    const float* x             = (const float*)d_in[0];
    const float* base_w        = (const float*)d_in[1];
    const float* base_b        = (const float*)d_in[2];
    const float* base_scale    = (const float*)d_in[3];
    const float* wavelet_scale = (const float*)d_in[4];
    const float* w_ll          = (const float*)d_in[5];
    const float* w_lh0         = (const float*)d_in[6];
    const float* w_hl0         = (const float*)d_in[7];
    const float* w_hh0         = (const float*)d_in[8];
    const float* w_lh1         = (const float*)d_in[9];
    const float* w_hl1         = (const float*)d_in[10];
    const float* w_hh1         = (const float*)d_in[11];
    float* out                 = (float*)d_out;

    dim3 grid(BB * CC * 16);
    dim3 block(256);
    hipLaunchKernelGGL(wtconv_fused, grid, block, 0, stream,
                       x, base_w, base_b, base_scale, wavelet_scale,
                       w_ll, w_lh0, w_hl0, w_hh0, w_lh1, w_hl1, w_hh1, out);
}

// Round 2
// 376.629 us; speedup vs baseline: 1.1571x; 1.1571x over previous
//
#include <hip/hip_runtime.h>

// WTConv2d fused (see R0 derivation):
// out = (conv3x3(x, base_w)+base_b)*base_scale
//     + wavelet_scale * U( U(conv3x3(t1, ws1)) + conv3x3(t0, ws0) )
// t0 = D(x), t1 = D(t0); D = stride-2 2x2 corr, +-0.25 signs by c>>6;
// U = 2x upsample, +-0.5 signs by c>>6; ws1 = w_ll+w_lh1+w_hl1+w_hh1,
// ws0 = w_lh0+w_hl0+w_hh0.
//
// R3 post-mortem: global re-read in phase 6 missed L2 (resident tiles+write
// stream thrash the 4MB XCD L2) -> +131MB fetch, +46us. Conflicts/occupancy
// proven NON-binding (both improved, VALU dropped). => latency-bound.
//
// R4: two-tile software pipeline per block (tiles horizontally adjacent,
// same channel). Both tiles' x loaded to REGISTERS in one burst up front;
// tile B's regs (16 VGPR) stay live under tile A's pyramid+phase6, hiding
// all global-load latency. t0(B) computed from regs DURING phase6(A)
// (t0s dead there); xs overwritten with B after one sync. LDS unchanged
// (27.1KB), 4 syncs/tile unchanged, weight setup amortized 2x.

#define HH 224
#define WW 224
#define CC 256
#define BB 4
#define XS_S 68   // xs row stride (floats)
#define T0_S 36   // t0s row stride

__global__ __launch_bounds__(256, 4) void wtconv_fused(
    const float* __restrict__ x,
    const float* __restrict__ base_w,
    const float* __restrict__ base_b,
    const float* __restrict__ base_scale,
    const float* __restrict__ wavelet_scale,
    const float* __restrict__ w_ll,
    const float* __restrict__ w_lh0,
    const float* __restrict__ w_hl0,
    const float* __restrict__ w_hh0,
    const float* __restrict__ w_lh1,
    const float* __restrict__ w_hl1,
    const float* __restrict__ w_hh1,
    float* __restrict__ out)
{
    __shared__ float xs[64][XS_S];   // x rows [R0-4, R0+60), cols [C0-4, C0+60)
    __shared__ float t0s[32][T0_S];  // t0 rows [A0-2, A0+30)
    __shared__ float t1s[16][18];    // t1 rows [A1-1, A1+15)
    __shared__ float a1s[14][14];    // a1 rows [A1, A1+14)
    __shared__ float a0s[28][28];    // a0 rows [A0, A0+28)
    // total 17408+4608+1152+784+3136 = 27088 B -> 5 blocks/CU

    const int tid  = threadIdx.x;
    const int bid  = blockIdx.x;
    const int pr   = bid & 7;            // tile pair (2pr, 2pr+1)
    const int c    = (bid >> 3) & 255;
    const int b    = bid >> 11;
    const int tA   = 2 * pr;
    const int ti   = tA >> 2;
    const int R0   = ti * 56;
    const int C0A  = (tA & 3) * 56;
    const int C0B  = C0A + 56;

    const int f = c >> 6;                   // faithful quirk: filter idx = c//64
    const float sR = (f & 1) ? -1.f : 1.f;
    const float sC = (f & 2) ? -1.f : 1.f;

    float ws1[9], ws0[9], bw[9];
#pragma unroll
    for (int j = 0; j < 9; ++j) {
        const int o = c * 9 + j;
        ws1[j] = w_ll[o] + w_lh1[o] + w_hl1[o] + w_hh1[o];
        ws0[j] = w_lh0[o] + w_hl0[o] + w_hh0[o];
        bw[j]  = base_w[o];
    }
    const float bb  = base_b[c];
    const float bsc = base_scale[c];
    const float wsc = wavelet_scale[c];

    const float* xp = x   + (size_t)(b * CC + c) * (HH * WW);
    float*       op = out + (size_t)(b * CC + c) * (HH * WW);

    // ---- load BOTH tiles' 64x64 x data into registers (one MLP burst) ----
    // thread: col-group k (float4), row-pair rp; covers rows
    // {2rp, 2rp+1, 2rp+32, 2rp+33} -> vertical pairs live in one thread.
    const int k  = tid & 15;
    const int rp = tid >> 4;
    float4 vA[4], vB[4];
    {
        const int gcA = C0A - 4 + 4 * k;
        const int gcB = C0B - 4 + 4 * k;
        const bool cokA = (gcA >= 0) & (gcA < WW);
        const bool cokB = (gcB < WW);        // gcB >= 52 always
#pragma unroll
        for (int it = 0; it < 4; ++it) {
            const int gr  = R0 - 4 + 2 * rp + (it & 1) + 32 * (it >> 1);
            const bool rok = (gr >= 0) & (gr < HH);
            float4 a = make_float4(0.f, 0.f, 0.f, 0.f);
            float4 bq = make_float4(0.f, 0.f, 0.f, 0.f);
            if (rok & cokA) a  = *(const float4*)(xp + gr * WW + gcA);
            if (rok & cokB) bq = *(const float4*)(xp + gr * WW + gcB);
            vA[it] = a; vB[it] = bq;
        }
    }

    // ---- helpers (shared LDS, tile-local coords identical for A and B) ----
    auto t0_store = [&](const float4* v) {
#pragma unroll
        for (int h = 0; h < 2; ++h) {
            const float4 v0 = v[2 * h];
            const float4 v1 = v[2 * h + 1];
            const float e = (v0.x + sC * v0.y) + sR * (v1.x + sC * v1.y);
            const float o = (v0.z + sC * v0.w) + sR * (v1.z + sC * v1.w);
            *(float2*)&t0s[rp + 16 * h][2 * k] = make_float2(0.25f * e, 0.25f * o);
        }
    };
    auto xs_store = [&](const float4* v) {
#pragma unroll
        for (int it = 0; it < 4; ++it) {
            const int row = 2 * rp + (it & 1) + 32 * (it >> 1);
            *(float4*)&xs[row][4 * k] = v[it];
        }
    };
    auto t1_phase = [&]() {
        if (tid < 64) {
            const int m = tid >> 2;
            const int n = 4 * (tid & 3);
            const float4 A  = *(const float4*)&t0s[2 * m][2 * n];
            const float4 Bq = *(const float4*)&t0s[2 * m][2 * n + 4];
            const float4 Cq = *(const float4*)&t0s[2 * m + 1][2 * n];
            const float4 Dq = *(const float4*)&t0s[2 * m + 1][2 * n + 4];
            const float v0v = 0.25f * ((A.x + sC * A.y) + sR * (Cq.x + sC * Cq.y));
            const float v1v = 0.25f * ((A.z + sC * A.w) + sR * (Cq.z + sC * Cq.w));
            const float v2v = 0.25f * ((Bq.x + sC * Bq.y) + sR * (Dq.x + sC * Dq.y));
            const float v3v = 0.25f * ((Bq.z + sC * Bq.w) + sR * (Dq.z + sC * Dq.w));
            *(float2*)&t1s[m][n]     = make_float2(v0v, v1v);
            *(float2*)&t1s[m][n + 2] = make_float2(v2v, v3v);
        }
    };
    auto a1_phase = [&]() {
        if (tid < 98) {
            const int kk = tid / 7;
            const int l  = 2 * (tid % 7);
            float acc0 = 0.f, acc1 = 0.f;
#pragma unroll
            for (int u = 0; u < 3; ++u) {
                const float2 p = *(const float2*)&t1s[kk + u][l];
                const float2 q = *(const float2*)&t1s[kk + u][l + 2];
                acc0 += p.x * ws1[3 * u] + p.y * ws1[3 * u + 1] + q.x * ws1[3 * u + 2];
                acc1 += p.y * ws1[3 * u] + q.x * ws1[3 * u + 1] + q.y * ws1[3 * u + 2];
            }
            *(float2*)&a1s[kk][l] = make_float2(acc0, acc1);
        }
    };
    auto a0_phase = [&]() {
        if (tid < 196) {
            const int i  = tid / 7;
            const int j7 = tid % 7;
            const int j  = 4 * j7;
            float a0 = 0.f, a1v = 0.f, a2 = 0.f, a3 = 0.f;
#pragma unroll
            for (int u = 0; u < 3; ++u) {
                const float4 A  = *(const float4*)&t0s[i + 1 + u][j];
                const float4 Bq = *(const float4*)&t0s[i + 1 + u][j + 4];
                const float c1 = A.y, c2 = A.z, c3 = A.w, c4 = Bq.x, c5 = Bq.y, c6 = Bq.z;
                const float w0 = ws0[3 * u], w1 = ws0[3 * u + 1], w2 = ws0[3 * u + 2];
                a0  += c1 * w0 + c2 * w1 + c3 * w2;
                a1v += c2 * w0 + c3 * w1 + c4 * w2;
                a2  += c3 * w0 + c4 * w1 + c5 * w2;
                a3  += c4 * w0 + c5 * w1 + c6 * w2;
            }
            const float2 ap = *(const float2*)&a1s[i >> 1][2 * j7];
            const float e = 0.5f * ((i & 1) ? sR : 1.f);
            const float o = e * sC;
            float4 r;
            r.x = a0  + e * ap.x;
            r.y = a1v + o * ap.x;
            r.z = a2  + e * ap.y;
            r.w = a3  + o * ap.y;
            *(float4*)&a0s[i][j] = r;
        }
    };
    auto phase6 = [&](int C0) {
        if (tid < 196) {
            const int cg   = tid % 14;
            const int band = tid / 14;
            const int r0   = 4 * band;
            const int xc   = 4 * cg + 3;     // leftmost tap col in xs
            float h[6][6];
#pragma unroll
            for (int rr = 0; rr < 6; ++rr) {
                const float* row = &xs[r0 + 3 + rr][0];
                const float  s0v = row[xc];
                const float4 q   = *(const float4*)&row[xc + 1];   // 16B aligned
                const float  s1v = row[xc + 5];
                h[rr][0] = s0v; h[rr][1] = q.x; h[rr][2] = q.y;
                h[rr][3] = q.z; h[rr][4] = q.w; h[rr][5] = s1v;
            }
            const float we = wsc * 0.5f;
#pragma unroll
            for (int rr = 0; rr < 4; ++rr) {
                const int r = r0 + rr;
                float acc[4];
#pragma unroll
                for (int t = 0; t < 4; ++t) {
                    acc[t] = h[rr][t]     * bw[0] + h[rr][t + 1]     * bw[1] + h[rr][t + 2]     * bw[2]
                           + h[rr + 1][t] * bw[3] + h[rr + 1][t + 1] * bw[4] + h[rr + 1][t + 2] * bw[5]
                           + h[rr + 2][t] * bw[6] + h[rr + 2][t + 1] * bw[7] + h[rr + 2][t + 2] * bw[8];
                }
                const float2 ap = *(const float2*)&a0s[r >> 1][2 * cg];
                const float w0 = (r & 1) ? we * sR : we;
                const float w1 = w0 * sC;
                float4 o;
                o.x = (acc[0] + bb) * bsc + w0 * ap.x;
                o.y = (acc[1] + bb) * bsc + w1 * ap.x;
                o.z = (acc[2] + bb) * bsc + w0 * ap.y;
                o.w = (acc[3] + bb) * bsc + w1 * ap.y;
                *(float4*)(op + (size_t)(R0 + r) * WW + C0 + 4 * cg) = o;
            }
        }
    };

    // ---- pipelined schedule: 9 regions, 8 syncs for 2 tiles ----
    xs_store(vA);
    t0_store(vA);
    __syncthreads();
    t1_phase();            // reads t0s(A), writes t1s
    __syncthreads();
    a1_phase();            // reads t1s, writes a1s
    __syncthreads();
    a0_phase();            // reads t0s(A)+a1s, writes a0s
    __syncthreads();
    phase6(C0A);           // reads xs(A)+a0s(A)  -> out
    t0_store(vB);          // writes t0s(B): t0s dead after a0_phase sync
    __syncthreads();
    xs_store(vB);          // xs dead after phase6(A)
    t1_phase();            // reads t0s(B)
    __syncthreads();
    a1_phase();
    __syncthreads();
    a0_phase();
    __syncthreads();
    phase6(C0B);
}

extern "C" void kernel_launch(void* const* d_in, const int* in_sizes, int n_in,
                              void* d_out, int out_size, void* d_ws, size_t ws_size,
                              hipStream_t stream) {
    const float* x             = (const float*)d_in[0];
    const float* base_w        = (const float*)d_in[1];
    const float* base_b        = (const float*)d_in[2];
    const float* base_scale    = (const float*)d_in[3];
    const float* wavelet_scale = (const float*)d_in[4];
    const float* w_ll          = (const float*)d_in[5];
    const float* w_lh0         = (const float*)d_in[6];
    const float* w_hl0         = (const float*)d_in[7];
    const float* w_hh0         = (const float*)d_in[8];
    const float* w_lh1         = (const float*)d_in[9];
    const float* w_hl1         = (const float*)d_in[10];
    const float* w_hh1         = (const float*)d_in[11];
    float* out                 = (float*)d_out;

    dim3 grid(BB * CC * 8);
    dim3 block(256);
    hipLaunchKernelGGL(wtconv_fused, grid, block, 0, stream,
                       x, base_w, base_b, base_scale, wavelet_scale,
                       w_ll, w_lh0, w_hl0, w_hh0, w_lh1, w_hl1, w_hh1, out);
}